// Round 2
// baseline (1134.937 us; speedup 1.0000x reference)
//
#include <hip/hip_runtime.h>

typedef __bf16 bf16;
typedef __attribute__((ext_vector_type(8))) __bf16 bf16x8;
typedef __attribute__((ext_vector_type(4))) __bf16 bf16x4;
typedef __attribute__((ext_vector_type(4))) float fvec4;
typedef __attribute__((ext_vector_type(4))) float fx4;

#define MFMA16(a, b, c) __builtin_amdgcn_mfma_f32_16x16x32_bf16(a, b, c, 0, 0, 0)

__device__ inline fx4 zero4() { fx4 z = {0.f, 0.f, 0.f, 0.f}; return z; }

// Workspace bf16 layout (elements):
//   wqkv : [1536][512]  q_w,k_w,v_w rows contiguous        @ 0        (786432)
//   wo   : [512][512]                                      @ 786432   (262144)
//   pq   : [8][128][64]                                    @ 1048576  (65536)
//   pk   : [8][128][64]                                    @ 1114112  (65536)
//   pv   : [8][128][64]                                    @ 1179648  (65536)
//   total prep elems = 1245184
#define PREP_ELEMS 1245184

// ---------------------------------------------------------------------------
// Prep: convert fp32 weights / positional tensors to bf16 in workspace.
// 608 blocks x 512 threads x 4 elems = 1,245,184 exactly.
// ---------------------------------------------------------------------------
__global__ __launch_bounds__(512) void prep_kernel(
    const float* __restrict__ qw, const float* __restrict__ kw,
    const float* __restrict__ vw, const float* __restrict__ ow,
    const float* __restrict__ pq, const float* __restrict__ pk,
    const float* __restrict__ pv, bf16* __restrict__ dst)
{
  int i = (blockIdx.x * 512 + threadIdx.x) * 4;
  const float* s;
  if      (i < 262144)  s = qw + i;
  else if (i < 524288)  s = kw + (i - 262144);
  else if (i < 786432)  s = vw + (i - 524288);
  else if (i < 1048576) s = ow + (i - 786432);
  else if (i < 1114112) s = pq + (i - 1048576);
  else if (i < 1179648) s = pk + (i - 1114112);
  else                  s = pv + (i - 1179648);
  fvec4 v = *(const fvec4*)s;
  bf16x4 o = { (bf16)v[0], (bf16)v[1], (bf16)v[2], (bf16)v[3] };
  *(bf16x4*)(dst + i) = o;
}

// ---------------------------------------------------------------------------
// Kernel 1: fused QKV projection. One workgroup per bh=(b,h).
// x fp32 [b][c][h][w] loaded as float4, converted to bf16, transposed into
// LDS At[w][c] (pitch 520 -> 16B-aligned rows). A-operand = At rows,
// B-operand = bf16 weight rows (wqkv, co contiguous across q/k/v).
// Outputs q,k,v bf16 as [lb][n][w][d].
// ---------------------------------------------------------------------------
__global__ __launch_bounds__(512, 1) void qkv_kernel(
    const float* __restrict__ x,
    const bf16* __restrict__ wqkv,
    const float* __restrict__ q_b, const float* __restrict__ k_b,
    const float* __restrict__ v_b,
    bf16* __restrict__ qo, bf16* __restrict__ ko, bf16* __restrict__ vo,
    int bh0)
{
  extern __shared__ bf16 At[];            // [128][520]
  const int PITCH = 520;
  const int lb = blockIdx.x;
  const int bh = bh0 + lb;
  const int b = bh >> 7, h = bh & 127;
  const int t = threadIdx.x;

  // stage + transpose + downconvert: x[b][c][h][w0..w0+3] -> At[w][c]
  const float* xb = x + (size_t)b * 512 * 16384 + h * 128;
  const int st = t & 3;                   // stagger to spread write banks
  #pragma unroll
  for (int it = 0; it < 32; ++it) {
    int idx = it * 512 + t;               // 16384 float4 chunks
    int c = idx >> 5;
    int w0 = (idx & 31) << 2;
    fvec4 v4 = *(const fvec4*)(xb + (size_t)c * 16384 + w0);
    #pragma unroll
    for (int ii = 0; ii < 4; ++ii) {
      int i = (ii + st) & 3;
      At[(w0 + i) * PITCH + c] = (bf16)v4[i];
    }
  }
  __syncthreads();

  const int wv = t >> 6, l = t & 63, lr = l & 15, lg = l >> 4;
  const int m0 = wv * 16;                 // this wave's w-tile

  for (int cog = 0; cog < 8; ++cog) {     // 8 groups of 192 output channels
    fx4 acc[12];
    #pragma unroll
    for (int i = 0; i < 12; ++i) acc[i] = zero4();

    for (int kc = 0; kc < 16; ++kc) {     // K = 512, steps of 32
      int c0 = kc * 32;
      bf16x8 af = *(const bf16x8*)(&At[(m0 + lr) * PITCH + c0 + lg * 8]);
      #pragma unroll
      for (int tt = 0; tt < 12; ++tt) {
        int co = cog * 192 + tt * 16;
        bf16x8 bfr = *(const bf16x8*)(wqkv + (size_t)(co + lr) * 512 + c0 + lg * 8);
        acc[tt] = MFMA16(af, bfr, acc[tt]);
      }
    }
    // epilogue: bias + store. D layout: col(co)=lr, row(w)=lg*4+r.
    #pragma unroll
    for (int tt = 0; tt < 12; ++tt) {
      int co = cog * 192 + tt * 16;       // 0..1535, tile base
      int cr = co & 511;
      const float* bias = (co < 512) ? q_b : ((co < 1024) ? k_b : v_b);
      bf16* op = (co < 512) ? qo : ((co < 1024) ? ko : vo);
      float bv = bias[cr + lr];
      int n = cr >> 6;
      int d = (cr & 63) + lr;
      size_t base = (((size_t)lb * 8 + n) * 128) * 64 + d;
      #pragma unroll
      for (int r = 0; r < 4; ++r) {
        int w = m0 + lg * 4 + r;
        op[base + (size_t)w * 64] = (bf16)(acc[tt][r] + bv);
      }
    }
  }
}

// ---------------------------------------------------------------------------
// Kernel 2: gated attention, one workgroup per (bh, head).
// S[i,j] = [q, gk*pk][i] . [k+gq*pq, k][j]   (K-dim 128)
// KP LDS = K' (128x128, pitch 136); reused as P after a barrier.
// Vt LDS = Vmix^T (64x128, pitch 136) so PV B-fragments are contiguous.
// ---------------------------------------------------------------------------
__global__ __launch_bounds__(512, 2) void attn_kernel(
    const bf16* __restrict__ qo, const bf16* __restrict__ ko, const bf16* __restrict__ vo,
    const bf16* __restrict__ posb,   // pq @0, pk @65536, pv @131072 (bf16)
    const float* __restrict__ g_q, const float* __restrict__ g_k,
    const float* __restrict__ g_v1, const float* __restrict__ g_v2,
    bf16* __restrict__ ao)
{
  __shared__ bf16 KP[128 * 136];
  __shared__ bf16 Vt[64 * 136];
  const int blk = blockIdx.x;
  const int lb = blk >> 3, n = blk & 7;
  const float gq = g_q[0], gk = g_k[0];
  const float gv1 = g_v1[0], gv2 = g_v2[0];
  const size_t hb = ((size_t)lb * 8 + n) * 128 * 64;
  const bf16* Qb = qo + hb;
  const bf16* Kb = ko + hb;
  const bf16* Vb = vo + hb;
  const bf16* pqb = posb + (size_t)n * 8192;
  const bf16* pkb = posb + 65536 + (size_t)n * 8192;
  const bf16* pvb = posb + 131072 + (size_t)n * 8192;
  const int t = threadIdx.x;

  // build K' = [k + gq*pq | k] and Vmix^T
  #pragma unroll
  for (int it = 0; it < 2; ++it) {
    int idx = it * 512 + t;
    int j = idx >> 3, d0 = (idx & 7) << 3;
    bf16x8 kv  = *(const bf16x8*)(Kb + j * 64 + d0);
    bf16x8 pq8 = *(const bf16x8*)(pqb + j * 64 + d0);
    bf16x8 r1;
    #pragma unroll
    for (int i = 0; i < 8; ++i) r1[i] = (bf16)((float)kv[i] + gq * (float)pq8[i]);
    *(bf16x8*)(&KP[j * 136 + d0]) = r1;
    *(bf16x8*)(&KP[j * 136 + 64 + d0]) = kv;
    bf16x8 vv  = *(const bf16x8*)(Vb + j * 64 + d0);
    bf16x8 pv8 = *(const bf16x8*)(pvb + j * 64 + d0);
    #pragma unroll
    for (int i = 0; i < 8; ++i)
      Vt[(d0 + i) * 136 + j] = (bf16)(gv1 * (float)vv[i] + gv2 * (float)pv8[i]);
  }
  __syncthreads();

  const int wv = t >> 6, l = t & 63, lr = l & 15, lg = l >> 4;
  const int i0 = wv * 16;                  // this wave's query-row tile

  // S = Q' K'^T
  fx4 s[8];
  #pragma unroll
  for (int i = 0; i < 8; ++i) s[i] = zero4();
  for (int kc = 0; kc < 4; ++kc) {
    bf16x8 af;
    if (kc < 2) {
      af = *(const bf16x8*)(Qb + (i0 + lr) * 64 + kc * 32 + lg * 8);
    } else {
      bf16x8 raw = *(const bf16x8*)(pkb + (i0 + lr) * 64 + (kc - 2) * 32 + lg * 8);
      #pragma unroll
      for (int i = 0; i < 8; ++i) af[i] = (bf16)(gk * (float)raw[i]);
    }
    #pragma unroll
    for (int jt = 0; jt < 8; ++jt) {
      bf16x8 bfr = *(const bf16x8*)(&KP[(jt * 16 + lr) * 136 + kc * 32 + lg * 8]);
      s[jt] = MFMA16(af, bfr, s[jt]);
    }
  }

  // softmax over j (row i = i0 + 4*lg + r lives in 16 lanes x 8 regs)
  const float scale = 0.125f;              // hd^-0.5
  float inv[4];
  #pragma unroll
  for (int r = 0; r < 4; ++r) {
    float m = -1e30f;
    #pragma unroll
    for (int jt = 0; jt < 8; ++jt) m = fmaxf(m, s[jt][r]);
    #pragma unroll
    for (int off = 1; off < 16; off <<= 1) m = fmaxf(m, __shfl_xor(m, off));
    float sm = 0.f;
    #pragma unroll
    for (int jt = 0; jt < 8; ++jt) {
      float e = __expf((s[jt][r] - m) * scale);
      s[jt][r] = e;
      sm += e;
    }
    #pragma unroll
    for (int off = 1; off < 16; off <<= 1) sm += __shfl_xor(sm, off);
    inv[r] = 1.f / sm;
  }
  __syncthreads();                         // everyone done reading KP
  #pragma unroll
  for (int r = 0; r < 4; ++r) {
    int i = i0 + lg * 4 + r;
    #pragma unroll
    for (int jt = 0; jt < 8; ++jt)
      KP[i * 136 + jt * 16 + lr] = (bf16)(s[jt][r] * inv[r]);
  }
  __syncthreads();

  // O = P Vmix
  fx4 o[4];
  #pragma unroll
  for (int i = 0; i < 4; ++i) o[i] = zero4();
  for (int kc = 0; kc < 4; ++kc) {
    bf16x8 af = *(const bf16x8*)(&KP[(i0 + lr) * 136 + kc * 32 + lg * 8]);
    #pragma unroll
    for (int dt = 0; dt < 4; ++dt) {
      bf16x8 bfr = *(const bf16x8*)(&Vt[(dt * 16 + lr) * 136 + kc * 32 + lg * 8]);
      o[dt] = MFMA16(af, bfr, o[dt]);
    }
  }
  // AO[lb][w=i][n*64+d]
  #pragma unroll
  for (int dt = 0; dt < 4; ++dt) {
    #pragma unroll
    for (int r = 0; r < 4; ++r) {
      int i = i0 + lg * 4 + r;
      ao[((size_t)lb * 128 + i) * 512 + n * 64 + dt * 16 + lr] = (bf16)o[dt][r];
    }
  }
}

// ---------------------------------------------------------------------------
// Kernel 3: output projection. AO[lb][w][c] bf16, K-chunked LDS staging.
// D-tile (M=co, N=w) so stores to out[b][co][h][w] (fp32) are row-coalesced.
// ---------------------------------------------------------------------------
__global__ __launch_bounds__(512, 2) void oproj_kernel(
    const bf16* __restrict__ ao, const bf16* __restrict__ wo,
    const float* __restrict__ o_b,
    float* __restrict__ out, int bh0)
{
  __shared__ bf16 Ac[128 * 136];           // c-chunk of AO, pitch 136
  const int lb = blockIdx.x;
  const int bh = bh0 + lb;
  const int b = bh >> 7, h = bh & 127;
  const int t = threadIdx.x;
  const int wv = t >> 6, l = t & 63, lr = l & 15, lg = l >> 4;
  const bf16* aob = ao + (size_t)lb * 128 * 512;

  fx4 acc[4][8];
  #pragma unroll
  for (int ct = 0; ct < 4; ++ct)
    #pragma unroll
    for (int wt = 0; wt < 8; ++wt) acc[ct][wt] = zero4();

  for (int ch = 0; ch < 4; ++ch) {         // K = 512 in chunks of 128
    __syncthreads();
    #pragma unroll
    for (int it = 0; it < 4; ++it) {
      int idx = it * 512 + t;
      int w = idx >> 4, c8 = (idx & 15) << 3;
      *(bf16x8*)(&Ac[w * 136 + c8]) =
          *(const bf16x8*)(aob + (size_t)w * 512 + ch * 128 + c8);
    }
    __syncthreads();
    for (int kc = 0; kc < 4; ++kc) {
      int c0 = ch * 128 + kc * 32;
      bf16x8 af[4];
      #pragma unroll
      for (int ct = 0; ct < 4; ++ct)
        af[ct] = *(const bf16x8*)(wo + (size_t)(wv * 64 + ct * 16 + lr) * 512 + c0 + lg * 8);
      #pragma unroll
      for (int wt = 0; wt < 8; ++wt) {
        bf16x8 bfr = *(const bf16x8*)(&Ac[(wt * 16 + lr) * 136 + kc * 32 + lg * 8]);
        #pragma unroll
        for (int ct = 0; ct < 4; ++ct)
          acc[ct][wt] = MFMA16(af[ct], bfr, acc[ct][wt]);
      }
    }
  }
  // epilogue: D col = w = wt*16+lr, row = co = wv*64 + ct*16 + lg*4 + r
  #pragma unroll
  for (int ct = 0; ct < 4; ++ct) {
    #pragma unroll
    for (int r = 0; r < 4; ++r) {
      int co = wv * 64 + ct * 16 + lg * 4 + r;
      float bv = o_b[co];
      size_t ob = (((size_t)b * 512 + co) * 128 + h) * 128;
      #pragma unroll
      for (int wt = 0; wt < 8; ++wt)
        out[ob + wt * 16 + lr] = acc[ct][wt][r] + bv;
    }
  }
}

// ---------------------------------------------------------------------------
extern "C" void kernel_launch(void* const* d_in, const int* in_sizes, int n_in,
                              void* d_out, int out_size, void* d_ws, size_t ws_size,
                              hipStream_t stream) {
  const float* x    = (const float*)d_in[0];
  const float* q_w  = (const float*)d_in[1];
  const float* q_b  = (const float*)d_in[2];
  const float* k_w  = (const float*)d_in[3];
  const float* k_b  = (const float*)d_in[4];
  const float* v_w  = (const float*)d_in[5];
  const float* v_b  = (const float*)d_in[6];
  const float* o_w  = (const float*)d_in[7];
  const float* o_b  = (const float*)d_in[8];
  const float* pos_q = (const float*)d_in[9];
  const float* pos_k = (const float*)d_in[10];
  const float* pos_v = (const float*)d_in[11];
  const float* g_q  = (const float*)d_in[12];
  const float* g_k  = (const float*)d_in[13];
  const float* g_v1 = (const float*)d_in[14];
  const float* g_v2 = (const float*)d_in[15];
  float* out = (float*)d_out;

  bf16* prep = (bf16*)d_ws;
  bf16* wqkv = prep;                         // 786432
  bf16* wo   = prep + 786432;                // 262144
  bf16* posb = prep + 1048576;               // 3*65536

  // per-bh bf16 buffers after prep region
  bf16* rest = prep + PREP_ELEMS;
  size_t avail = (ws_size > (size_t)PREP_ELEMS * 2) ? ws_size - (size_t)PREP_ELEMS * 2 : 0;
  const size_t per_bh = (size_t)4 * 65536 * sizeof(bf16);  // q,k,v,ao
  int nbh = (int)(avail / per_bh);
  if (nbh > 512) nbh = 512;
  if (nbh < 1) nbh = 1;

  bf16* qo = rest;
  bf16* ko = qo + (size_t)nbh * 65536;
  bf16* vo = ko + (size_t)nbh * 65536;
  bf16* ao = vo + (size_t)nbh * 65536;

  (void)hipFuncSetAttribute((const void*)qkv_kernel,
                            hipFuncAttributeMaxDynamicSharedMemorySize, 133120);

  prep_kernel<<<608, 512, 0, stream>>>(q_w, k_w, v_w, o_w, pos_q, pos_k, pos_v, prep);

  for (int bh0 = 0; bh0 < 512; bh0 += nbh) {
    int cur = (512 - bh0 < nbh) ? (512 - bh0) : nbh;
    qkv_kernel<<<cur, 512, 133120, stream>>>(x, wqkv, q_b, k_b, v_b,
                                             qo, ko, vo, bh0);
    attn_kernel<<<cur * 8, 512, 0, stream>>>(qo, ko, vo, posb,
                                             g_q, g_k, g_v1, g_v2, ao);
    oproj_kernel<<<cur, 512, 0, stream>>>(ao, wo, o_b, out, bh0);
  }
}

// Round 3
// 515.594 us; speedup vs baseline: 2.2012x; 2.2012x over previous
//
#include <hip/hip_runtime.h>

typedef __bf16 bf16;
typedef __attribute__((ext_vector_type(8))) __bf16 bf16x8;
typedef __attribute__((ext_vector_type(4))) __bf16 bf16x4;
typedef __attribute__((ext_vector_type(4))) float fvec4;

#define MFMA16(a, b, c) __builtin_amdgcn_mfma_f32_16x16x32_bf16(a, b, c, 0, 0, 0)

__device__ __forceinline__ void glds16(const bf16* g, bf16* l) {
  __builtin_amdgcn_global_load_lds(
      (const __attribute__((address_space(1))) void*)g,
      (__attribute__((address_space(3))) void*)l, 16, 0, 0);
}

__device__ inline fvec4 zero4() { fvec4 z = {0.f, 0.f, 0.f, 0.f}; return z; }

// Workspace bf16 layout (elements):
//   wqkv : [1536][512] q/k/v rows contiguous @ 0        (786432)
//   wo   : [512][512]                        @ 786432   (262144)
//   posb : pq/pk/pv [8][128][64] each        @ 1048576  (196608)
#define PREP_ELEMS 1245184

__global__ __launch_bounds__(512) void prep_kernel(
    const float* __restrict__ qw, const float* __restrict__ kw,
    const float* __restrict__ vw, const float* __restrict__ ow,
    const float* __restrict__ pq, const float* __restrict__ pk,
    const float* __restrict__ pv, bf16* __restrict__ dst)
{
  int i = (blockIdx.x * 512 + threadIdx.x) * 4;
  const float* s;
  if      (i < 262144)  s = qw + i;
  else if (i < 524288)  s = kw + (i - 262144);
  else if (i < 786432)  s = vw + (i - 524288);
  else if (i < 1048576) s = ow + (i - 786432);
  else if (i < 1114112) s = pq + (i - 1048576);
  else if (i < 1179648) s = pk + (i - 1114112);
  else                  s = pv + (i - 1179648);
  fvec4 v = *(const fvec4*)s;
  bf16x4 o = { (bf16)v[0], (bf16)v[1], (bf16)v[2], (bf16)v[3] };
  *(bf16x4*)(dst + i) = o;
}

// ---------------------------------------------------------------------------
// Transpose/convert: x fp32 [b][c][h][w] -> xt bf16 [(lb*128+w)][512].
// Block = (c-chunk of 64, lb). LDS fp32 tile pitch 133 (read phase ~2-way).
// ---------------------------------------------------------------------------
__global__ __launch_bounds__(256) void xpose_kernel(
    const float* __restrict__ x, bf16* __restrict__ xt, int bh0)
{
  __shared__ float Xs[64 * 133];
  const int cb = blockIdx.x, lb = blockIdx.y;
  const int bh = bh0 + lb, b = bh >> 7, h = bh & 127;
  const int t = threadIdx.x;
  const float* xb = x + (size_t)b * 8388608 + (size_t)(cb * 64) * 16384 + h * 128;
  #pragma unroll
  for (int it = 0; it < 8; ++it) {
    int idx = it * 256 + t;
    int c = idx >> 5, w4 = (idx & 31) << 2;
    fvec4 v = *(const fvec4*)(xb + (size_t)c * 16384 + w4);
    #pragma unroll
    for (int j = 0; j < 4; ++j) Xs[c * 133 + w4 + j] = v[j];
  }
  __syncthreads();
  const int c0 = (t & 7) * 8, wsub = t >> 3;
  #pragma unroll
  for (int wb = 0; wb < 4; ++wb) {
    int w = wb * 32 + wsub;
    bf16x8 o;
    #pragma unroll
    for (int i = 0; i < 8; ++i) o[i] = (bf16)Xs[(c0 + i) * 133 + w];
    *(bf16x8*)(xt + ((size_t)lb * 128 + w) * 512 + cb * 64 + c0) = o;
  }
}

// ---------------------------------------------------------------------------
// QKV GEMM: C[m=bh*w][n=co 1536] = xt @ wqkv^T. 128x128 tile, BK=64,
// global_load_lds(16B) staging, XOR col-swizzle (c16 ^ row&7) -> LDS reads
// at bank-BW floor. Epilogue adds bias, stores row-major [m][1536].
// ---------------------------------------------------------------------------
__global__ __launch_bounds__(256, 3) void qkvgemm_kernel(
    const bf16* __restrict__ xt, const bf16* __restrict__ wqkv,
    const float* __restrict__ q_b, const float* __restrict__ k_b,
    const float* __restrict__ v_b, bf16* __restrict__ qkvbuf)
{
  __shared__ bf16 As[128 * 64];
  __shared__ bf16 Bs[128 * 64];
  const int nt0 = blockIdx.x * 128;
  const int m0 = blockIdx.y * 128;
  const int t = threadIdx.x;
  const int wv = t >> 6, lane = t & 63;
  const int lr = lane & 15, lg = lane >> 4;
  const int wm = wv >> 1, wn = wv & 1;
  const int srow = lane >> 3, c16 = lane & 7;

  fvec4 acc[4][4];
  #pragma unroll
  for (int i = 0; i < 4; ++i)
    #pragma unroll
    for (int j = 0; j < 4; ++j) acc[i][j] = zero4();

  for (int k0 = 0; k0 < 512; k0 += 64) {
    __syncthreads();
    #pragma unroll
    for (int j = 0; j < 4; ++j) {
      int seg = wv * 4 + j;
      int row = seg * 8 + srow;
      int cs = c16 ^ (row & 7);
      glds16(xt + (size_t)(m0 + row) * 512 + k0 + cs * 8, As + seg * 512);
      glds16(wqkv + (size_t)(nt0 + row) * 512 + k0 + cs * 8, Bs + seg * 512);
    }
    __syncthreads();
    #pragma unroll
    for (int kc = 0; kc < 2; ++kc) {
      bf16x8 af[4], bfv[4];
      #pragma unroll
      for (int mt = 0; mt < 4; ++mt) {
        int row = wm * 64 + mt * 16 + lr;
        int cs = (kc * 4 + lg) ^ (row & 7);
        af[mt] = *(const bf16x8*)(As + row * 64 + cs * 8);
      }
      #pragma unroll
      for (int nt = 0; nt < 4; ++nt) {
        int row = wn * 64 + nt * 16 + lr;
        int cs = (kc * 4 + lg) ^ (row & 7);
        bfv[nt] = *(const bf16x8*)(Bs + row * 64 + cs * 8);
      }
      #pragma unroll
      for (int mt = 0; mt < 4; ++mt)
        #pragma unroll
        for (int nt = 0; nt < 4; ++nt)
          acc[mt][nt] = MFMA16(af[mt], bfv[nt], acc[mt][nt]);
    }
  }
  #pragma unroll
  for (int nt = 0; nt < 4; ++nt) {
    int col = nt0 + wn * 64 + nt * 16 + lr;
    int cr = col & 511;
    const float* bias = (col < 512) ? q_b : ((col < 1024) ? k_b : v_b);
    float bv = bias[cr];
    #pragma unroll
    for (int mt = 0; mt < 4; ++mt) {
      int mb = m0 + wm * 64 + mt * 16 + lg * 4;
      #pragma unroll
      for (int r = 0; r < 4; ++r)
        qkvbuf[(size_t)(mb + r) * 1536 + col] = (bf16)(acc[mt][nt][r] + bv);
    }
  }
}

// ---------------------------------------------------------------------------
// Gated attention (unchanged math; Q/K/V read from qkvbuf rows, pitch 1536).
// S[i,j] = [q, gk*pk][i] . [k+gq*pq, k][j]; KP reused as P; Vt = Vmix^T.
// ---------------------------------------------------------------------------
__global__ __launch_bounds__(512, 2) void attn_kernel(
    const bf16* __restrict__ qkvbuf, const bf16* __restrict__ posb,
    const float* __restrict__ g_q, const float* __restrict__ g_k,
    const float* __restrict__ g_v1, const float* __restrict__ g_v2,
    bf16* __restrict__ ao)
{
  __shared__ bf16 KP[128 * 136];
  __shared__ bf16 Vt[64 * 136];
  const int blk = blockIdx.x;
  const int lb = blk >> 3, n = blk & 7;
  const float gq = g_q[0], gk = g_k[0];
  const float gv1 = g_v1[0], gv2 = g_v2[0];
  const bf16* Qb = qkvbuf + (size_t)(lb * 128) * 1536 + n * 64;
  const bf16* Kb = Qb + 512;
  const bf16* Vb = Qb + 1024;
  const bf16* pqb = posb + (size_t)n * 8192;
  const bf16* pkb = posb + 65536 + (size_t)n * 8192;
  const bf16* pvb = posb + 131072 + (size_t)n * 8192;
  const int t = threadIdx.x;

  #pragma unroll
  for (int it = 0; it < 2; ++it) {
    int idx = it * 512 + t;
    int j = idx >> 3, d0 = (idx & 7) << 3;
    bf16x8 kv  = *(const bf16x8*)(Kb + (size_t)j * 1536 + d0);
    bf16x8 pq8 = *(const bf16x8*)(pqb + j * 64 + d0);
    bf16x8 r1;
    #pragma unroll
    for (int i = 0; i < 8; ++i) r1[i] = (bf16)((float)kv[i] + gq * (float)pq8[i]);
    *(bf16x8*)(&KP[j * 136 + d0]) = r1;
    *(bf16x8*)(&KP[j * 136 + 64 + d0]) = kv;
    bf16x8 vv  = *(const bf16x8*)(Vb + (size_t)j * 1536 + d0);
    bf16x8 pv8 = *(const bf16x8*)(pvb + j * 64 + d0);
    #pragma unroll
    for (int i = 0; i < 8; ++i)
      Vt[(d0 + i) * 136 + j] = (bf16)(gv1 * (float)vv[i] + gv2 * (float)pv8[i]);
  }
  __syncthreads();

  const int wv = t >> 6, l = t & 63, lr = l & 15, lg = l >> 4;
  const int i0 = wv * 16;

  fvec4 s[8];
  #pragma unroll
  for (int i = 0; i < 8; ++i) s[i] = zero4();
  for (int kc = 0; kc < 4; ++kc) {
    bf16x8 af;
    if (kc < 2) {
      af = *(const bf16x8*)(Qb + (size_t)(i0 + lr) * 1536 + kc * 32 + lg * 8);
    } else {
      bf16x8 raw = *(const bf16x8*)(pkb + (i0 + lr) * 64 + (kc - 2) * 32 + lg * 8);
      #pragma unroll
      for (int i = 0; i < 8; ++i) af[i] = (bf16)(gk * (float)raw[i]);
    }
    #pragma unroll
    for (int jt = 0; jt < 8; ++jt) {
      bf16x8 bfr = *(const bf16x8*)(&KP[(jt * 16 + lr) * 136 + kc * 32 + lg * 8]);
      s[jt] = MFMA16(af, bfr, s[jt]);
    }
  }

  const float scale = 0.125f;
  float inv[4];
  #pragma unroll
  for (int r = 0; r < 4; ++r) {
    float m = -1e30f;
    #pragma unroll
    for (int jt = 0; jt < 8; ++jt) m = fmaxf(m, s[jt][r]);
    #pragma unroll
    for (int off = 1; off < 16; off <<= 1) m = fmaxf(m, __shfl_xor(m, off));
    float sm = 0.f;
    #pragma unroll
    for (int jt = 0; jt < 8; ++jt) {
      float e = __expf((s[jt][r] - m) * scale);
      s[jt][r] = e;
      sm += e;
    }
    #pragma unroll
    for (int off = 1; off < 16; off <<= 1) sm += __shfl_xor(sm, off);
    inv[r] = 1.f / sm;
  }
  __syncthreads();
  #pragma unroll
  for (int r = 0; r < 4; ++r) {
    int i = i0 + lg * 4 + r;
    #pragma unroll
    for (int jt = 0; jt < 8; ++jt)
      KP[i * 136 + jt * 16 + lr] = (bf16)(s[jt][r] * inv[r]);
  }
  __syncthreads();

  fvec4 o[4];
  #pragma unroll
  for (int i = 0; i < 4; ++i) o[i] = zero4();
  for (int kc = 0; kc < 4; ++kc) {
    bf16x8 af = *(const bf16x8*)(&KP[(i0 + lr) * 136 + kc * 32 + lg * 8]);
    #pragma unroll
    for (int dt = 0; dt < 4; ++dt) {
      bf16x8 bfr = *(const bf16x8*)(&Vt[(dt * 16 + lr) * 136 + kc * 32 + lg * 8]);
      o[dt] = MFMA16(af, bfr, o[dt]);
    }
  }
  #pragma unroll
  for (int dt = 0; dt < 4; ++dt) {
    #pragma unroll
    for (int r = 0; r < 4; ++r) {
      int i = i0 + lg * 4 + r;
      ao[((size_t)lb * 128 + i) * 512 + n * 64 + dt * 16 + lr] = (bf16)o[dt][r];
    }
  }
}

// ---------------------------------------------------------------------------
// O-proj GEMM: same structure; A = wo (m=co, so fp32 out stores are
// w-coalesced), B = ao rows (n=w). Epilogue adds o_b, writes out[b][co][h][w].
// ---------------------------------------------------------------------------
__global__ __launch_bounds__(256, 3) void oproj_kernel(
    const bf16* __restrict__ ao, const bf16* __restrict__ wo,
    const float* __restrict__ o_b, float* __restrict__ out, int bh0)
{
  __shared__ bf16 As[128 * 64];
  __shared__ bf16 Bs[128 * 64];
  const int ct4 = blockIdx.x;                // co tile (0..3)
  const int lb = blockIdx.y;
  const int bh = bh0 + lb, b = bh >> 7, h = bh & 127;
  const int t = threadIdx.x;
  const int wv = t >> 6, lane = t & 63;
  const int lr = lane & 15, lg = lane >> 4;
  const int wm = wv >> 1, wn = wv & 1;
  const int srow = lane >> 3, c16 = lane & 7;

  fvec4 acc[4][4];
  #pragma unroll
  for (int i = 0; i < 4; ++i)
    #pragma unroll
    for (int j = 0; j < 4; ++j) acc[i][j] = zero4();

  for (int k0 = 0; k0 < 512; k0 += 64) {
    __syncthreads();
    #pragma unroll
    for (int j = 0; j < 4; ++j) {
      int seg = wv * 4 + j;
      int row = seg * 8 + srow;
      int cs = c16 ^ (row & 7);
      glds16(wo + (size_t)(ct4 * 128 + row) * 512 + k0 + cs * 8, As + seg * 512);
      glds16(ao + ((size_t)lb * 128 + row) * 512 + k0 + cs * 8, Bs + seg * 512);
    }
    __syncthreads();
    #pragma unroll
    for (int kc = 0; kc < 2; ++kc) {
      bf16x8 af[4], bfv[4];
      #pragma unroll
      for (int mt = 0; mt < 4; ++mt) {
        int row = wm * 64 + mt * 16 + lr;
        int cs = (kc * 4 + lg) ^ (row & 7);
        af[mt] = *(const bf16x8*)(As + row * 64 + cs * 8);
      }
      #pragma unroll
      for (int nt = 0; nt < 4; ++nt) {
        int row = wn * 64 + nt * 16 + lr;
        int cs = (kc * 4 + lg) ^ (row & 7);
        bfv[nt] = *(const bf16x8*)(Bs + row * 64 + cs * 8);
      }
      #pragma unroll
      for (int mt = 0; mt < 4; ++mt)
        #pragma unroll
        for (int nt = 0; nt < 4; ++nt)
          acc[mt][nt] = MFMA16(af[mt], bfv[nt], acc[mt][nt]);
    }
  }
  #pragma unroll
  for (int mt = 0; mt < 4; ++mt) {
    #pragma unroll
    for (int r = 0; r < 4; ++r) {
      int co = ct4 * 128 + wm * 64 + mt * 16 + lg * 4 + r;
      float bv = o_b[co];
      size_t ob = ((size_t)(b * 512 + co) * 128 + h) * 128;
      #pragma unroll
      for (int nt = 0; nt < 4; ++nt) {
        int w = wn * 64 + nt * 16 + lr;
        out[ob + w] = acc[mt][nt][r] + bv;
      }
    }
  }
}

// ---------------------------------------------------------------------------
extern "C" void kernel_launch(void* const* d_in, const int* in_sizes, int n_in,
                              void* d_out, int out_size, void* d_ws, size_t ws_size,
                              hipStream_t stream) {
  const float* x    = (const float*)d_in[0];
  const float* q_w  = (const float*)d_in[1];
  const float* q_b  = (const float*)d_in[2];
  const float* k_w  = (const float*)d_in[3];
  const float* k_b  = (const float*)d_in[4];
  const float* v_w  = (const float*)d_in[5];
  const float* v_b  = (const float*)d_in[6];
  const float* o_w  = (const float*)d_in[7];
  const float* o_b  = (const float*)d_in[8];
  const float* pos_q = (const float*)d_in[9];
  const float* pos_k = (const float*)d_in[10];
  const float* pos_v = (const float*)d_in[11];
  const float* g_q  = (const float*)d_in[12];
  const float* g_k  = (const float*)d_in[13];
  const float* g_v1 = (const float*)d_in[14];
  const float* g_v2 = (const float*)d_in[15];
  float* out = (float*)d_out;

  bf16* prep = (bf16*)d_ws;
  bf16* wqkv = prep;                       // 786432
  bf16* wo   = prep + 786432;              // 262144
  bf16* posb = prep + 1048576;             // 196608

  bf16* rest = prep + PREP_ELEMS;
  size_t avail = (ws_size > (size_t)PREP_ELEMS * 2) ? ws_size - (size_t)PREP_ELEMS * 2 : 0;
  // per bh: xt/ao (128*512) + qkvbuf (128*1536), bf16 -> 512 KB
  const size_t per_bh = (size_t)(65536 + 196608) * sizeof(bf16);
  int nbh = (int)(avail / per_bh);
  if (nbh > 512) nbh = 512;
  if (nbh < 1) nbh = 1;

  bf16* xt = rest;                                  // nbh*65536 (aliased as ao)
  bf16* qkvbuf = xt + (size_t)nbh * 65536;          // nbh*196608

  prep_kernel<<<608, 512, 0, stream>>>(q_w, k_w, v_w, o_w, pos_q, pos_k, pos_v, prep);

  for (int bh0 = 0; bh0 < 512; bh0 += nbh) {
    int cur = (512 - bh0 < nbh) ? (512 - bh0) : nbh;
    xpose_kernel<<<dim3(8, cur), 256, 0, stream>>>(x, xt, bh0);
    qkvgemm_kernel<<<dim3(12, cur), 256, 0, stream>>>(xt, wqkv, q_b, k_b, v_b, qkvbuf);
    attn_kernel<<<cur * 8, 512, 0, stream>>>(qkvbuf, posb, g_q, g_k, g_v1, g_v2, xt);
    oproj_kernel<<<dim3(4, cur), 256, 0, stream>>>(xt, wo, o_b, out, bh0);
  }
}